// Round 1
// baseline (7213.548 us; speedup 1.0000x reference)
//
#include <hip/hip_runtime.h>
#include <math.h>

#define F_IN 512
#define H_DIM 64
#define C_DIM 16
#define K_HOPS 10
#define MLP_BLOCK 256
#define KCHUNK 32

// ---------------- degree / normalization ----------------

__global__ void deg_init_kernel(float* __restrict__ deg, int n) {
    int i = blockIdx.x * blockDim.x + threadIdx.x;
    if (i < n) deg[i] = 1.0f;  // self-loop
}

__global__ void deg_hist_kernel(const int* __restrict__ cols, float* __restrict__ deg, int e) {
    int i = blockIdx.x * blockDim.x + threadIdx.x;
    if (i < e) atomicAdd(&deg[cols[i]], 1.0f);
}

__global__ void dis_kernel(float* __restrict__ deg, int n) {
    int i = blockIdx.x * blockDim.x + threadIdx.x;
    if (i < n) deg[i] = rsqrtf(deg[i]);  // deg >= 1 always (self-loops)
}

// ---------------- MLP: out = relu(x@W1+b1)@W2+b2 ----------------
// One thread per row. x staged through LDS (coalesced); W1/W2 indices are
// wave-uniform -> expect s_load scalarization.

__global__ void mlp_kernel(const float* __restrict__ x,
                           const float* __restrict__ W1,
                           const float* __restrict__ b1,
                           const float* __restrict__ W2,
                           const float* __restrict__ b2,
                           float* __restrict__ out, int n) {
    __shared__ float xs[MLP_BLOCK][KCHUNK + 1];
    const int tid = threadIdx.x;
    const int row0 = blockIdx.x * MLP_BLOCK;
    const int row = row0 + tid;

    float acc[H_DIM];
#pragma unroll
    for (int j = 0; j < H_DIM; ++j) acc[j] = 0.0f;

    for (int c = 0; c < F_IN / KCHUNK; ++c) {
        __syncthreads();
        // stage 256 rows x 32 cols; 32 consecutive lanes read 128B of one row
#pragma unroll
        for (int i = 0; i < KCHUNK; ++i) {
            int r = (i << 3) + (tid >> 5);
            int kk = tid & 31;
            int gr = row0 + r;
            if (gr >= n) gr = n - 1;
            xs[r][kk] = x[(long)gr * F_IN + c * KCHUNK + kk];
        }
        __syncthreads();
        for (int kk = 0; kk < KCHUNK; ++kk) {
            float xv = xs[tid][kk];
            const float* wr = W1 + (c * KCHUNK + kk) * H_DIM;
#pragma unroll
            for (int j = 0; j < H_DIM; ++j)
                acc[j] = fmaf(xv, wr[j], acc[j]);
        }
    }

#pragma unroll
    for (int j = 0; j < H_DIM; ++j) {
        float v = acc[j] + b1[j];
        acc[j] = v > 0.0f ? v : 0.0f;
    }

    if (row < n) {
        float o[C_DIM];
#pragma unroll
        for (int j = 0; j < C_DIM; ++j) o[j] = b2[j];
#pragma unroll
        for (int k = 0; k < H_DIM; ++k) {
            float hv = acc[k];
            const float* w2r = W2 + k * C_DIM;
#pragma unroll
            for (int j = 0; j < C_DIM; ++j)
                o[j] = fmaf(hv, w2r[j], o[j]);
        }
#pragma unroll
        for (int j = 0; j < C_DIM; j += 4) {
            float4 v = make_float4(o[j], o[j + 1], o[j + 2], o[j + 3]);
            *(float4*)(out + (long)row * C_DIM + j) = v;
        }
    }
}

// ---------------- Riemann normalize + hidden accum + self-loop re-init ----
// 4 threads per node, one float4 (feature quad) each.
// agg in: raw aggregated h; out: dis^2 * h_normalized (self-loop base for
// the NEXT scatter). h out: normalized. hidden (+)= temp[tidx]*h_norm.

__global__ void norm_kernel(float* __restrict__ agg,
                            float* __restrict__ h,
                            float* __restrict__ hidden,
                            const float* __restrict__ dis,
                            const float* __restrict__ w_for_norm,
                            const float* __restrict__ temp,
                            int tidx, int first, int n) {
    int t = blockIdx.x * blockDim.x + threadIdx.x;
    int node = t >> 2, q = t & 3;
    if (node >= n) return;
    long base = (long)node * C_DIM + q * 4;
    float4 a = *(const float4*)(agg + base);
    float4 w = *(const float4*)(w_for_norm + q * 4);
    float pd = a.x * a.x * fabsf(w.x) + a.y * a.y * fabsf(w.y) +
               a.z * a.z * fabsf(w.z) + a.w * a.w * fabsf(w.w);
    pd += __shfl_xor(pd, 1);
    pd += __shfl_xor(pd, 2);
    float inv = 1.0f / (sqrtf(pd + 0.01f) + 0.01f);
    float4 hn = make_float4(a.x * inv, a.y * inv, a.z * inv, a.w * inv);
    *(float4*)(h + base) = hn;

    float tk = temp[tidx];
    float4 hv;
    if (first) hv = make_float4(0.f, 0.f, 0.f, 0.f);
    else hv = *(const float4*)(hidden + base);
    hv.x = fmaf(tk, hn.x, hv.x);
    hv.y = fmaf(tk, hn.y, hv.y);
    hv.z = fmaf(tk, hn.z, hv.z);
    hv.w = fmaf(tk, hn.w, hv.w);
    *(float4*)(hidden + base) = hv;

    float d = dis[node];
    float d2 = d * d;
    *(float4*)(agg + base) =
        make_float4(d2 * hn.x, d2 * hn.y, d2 * hn.z, d2 * hn.w);
}

// ---------------- scatter: agg[col] += dis[row]*dis[col] * h[row] ----------

__global__ void scatter_kernel(const int* __restrict__ rows,
                               const int* __restrict__ cols,
                               const float* __restrict__ dis,
                               const float* __restrict__ h,
                               float* __restrict__ agg, int e) {
    int t = blockIdx.x * blockDim.x + threadIdx.x;
    int ed = t >> 2, q = t & 3;
    if (ed >= e) return;
    int r = rows[ed], c = cols[ed];
    float nr = dis[r] * dis[c];
    float4 hv = *(const float4*)(h + (long)r * C_DIM + q * 4);
    float* dst = agg + (long)c * C_DIM + q * 4;
    atomicAdd(dst + 0, nr * hv.x);
    atomicAdd(dst + 1, nr * hv.y);
    atomicAdd(dst + 2, nr * hv.z);
    atomicAdd(dst + 3, nr * hv.w);
}

// ---------------- launch ----------------

extern "C" void kernel_launch(void* const* d_in, const int* in_sizes, int n_in,
                              void* d_out, int out_size, void* d_ws, size_t ws_size,
                              hipStream_t stream) {
    const float* x          = (const float*)d_in[0];
    const int*   edge_index = (const int*)d_in[1];
    const float* W1         = (const float*)d_in[2];
    const float* b1         = (const float*)d_in[3];
    const float* W2         = (const float*)d_in[4];
    const float* b2         = (const float*)d_in[5];
    const float* temp       = (const float*)d_in[6];
    const float* w_for_norm = (const float*)d_in[7];
    float* hidden = (float*)d_out;

    const int n = in_sizes[0] / F_IN;
    const int e = in_sizes[1] / 2;

    float* ws  = (float*)d_ws;
    float* dis = ws;                         // n floats (deg, then rsqrt in place)
    float* h   = ws + n;                     // n*16
    float* agg = ws + n + (long)n * C_DIM;   // n*16

    const int* rows = edge_index;       // sources
    const int* cols = edge_index + e;   // destinations

    const int B = 256;
    deg_init_kernel<<<(n + B - 1) / B, B, 0, stream>>>(dis, n);
    deg_hist_kernel<<<(e + B - 1) / B, B, 0, stream>>>(cols, dis, e);
    dis_kernel<<<(n + B - 1) / B, B, 0, stream>>>(dis, n);

    mlp_kernel<<<(n + MLP_BLOCK - 1) / MLP_BLOCK, MLP_BLOCK, 0, stream>>>(
        x, W1, b1, W2, b2, agg, n);

    norm_kernel<<<(4 * n + B - 1) / B, B, 0, stream>>>(
        agg, h, hidden, dis, w_for_norm, temp, 0, 1, n);

    for (int k = 0; k < K_HOPS; ++k) {
        scatter_kernel<<<(4 * e + B - 1) / B, B, 0, stream>>>(
            rows, cols, dis, h, agg, e);
        norm_kernel<<<(4 * n + B - 1) / B, B, 0, stream>>>(
            agg, h, hidden, dis, w_for_norm, temp, k + 1, 0, n);
    }
}

// Round 2
// 1480.948 us; speedup vs baseline: 4.8709x; 4.8709x over previous
//
#include <hip/hip_runtime.h>
#include <math.h>

#define F_IN 512
#define HD 64
#define CD 16
#define K_HOPS 10
#define PAD 68

// ---------------- CSR build ----------------

__global__ void zero_int_kernel(int* __restrict__ p, int n) {
    int i = blockIdx.x * blockDim.x + threadIdx.x;
    if (i < n) p[i] = 0;
}

__global__ void hist_kernel(const int* __restrict__ cols, int* __restrict__ degi, int e) {
    int i = blockIdx.x * blockDim.x + threadIdx.x;
    if (i < e) atomicAdd(&degi[cols[i]], 1);
}

__global__ void dis_kernel(const int* __restrict__ degi, float* __restrict__ dis, int n) {
    int i = blockIdx.x * blockDim.x + threadIdx.x;
    if (i < n) dis[i] = rsqrtf((float)(degi[i] + 1));  // +1 self-loop
}

// two-level exclusive scan over degi (chunk = 1024 elements / block)
__global__ void scan1_kernel(const int* __restrict__ degi, int* __restrict__ bsum, int n) {
    __shared__ int sd[256];
    int b = blockIdx.x, t = threadIdx.x;
    int base = b * 1024 + t * 4;
    int s = 0;
#pragma unroll
    for (int i = 0; i < 4; ++i) { int idx = base + i; if (idx < n) s += degi[idx]; }
    sd[t] = s; __syncthreads();
    for (int off = 128; off > 0; off >>= 1) {
        if (t < off) sd[t] += sd[t + off];
        __syncthreads();
    }
    if (t == 0) bsum[b] = sd[0];
}

__global__ void scan2_kernel(const int* __restrict__ bsum, int* __restrict__ bpre, int nb) {
    __shared__ int sd[256];
    int t = threadIdx.x;
    int v = (t < nb) ? bsum[t] : 0;
    sd[t] = v; __syncthreads();
    for (int off = 1; off < 256; off <<= 1) {
        int x = (t >= off) ? sd[t - off] : 0;
        __syncthreads();
        sd[t] += x;
        __syncthreads();
    }
    bpre[t] = sd[t] - v;  // exclusive
}

__global__ void scan3_kernel(const int* __restrict__ degi, const int* __restrict__ bpre,
                             int* __restrict__ rowstart, int* __restrict__ cursor,
                             int n, int e) {
    __shared__ int sd[256];
    int b = blockIdx.x, t = threadIdx.x;
    int base = b * 1024 + t * 4;
    int v[4]; int s = 0;
#pragma unroll
    for (int i = 0; i < 4; ++i) { int idx = base + i; v[i] = (idx < n) ? degi[idx] : 0; s += v[i]; }
    sd[t] = s; __syncthreads();
    for (int off = 1; off < 256; off <<= 1) {
        int x = (t >= off) ? sd[t - off] : 0;
        __syncthreads();
        sd[t] += x;
        __syncthreads();
    }
    int excl = sd[t] - s + bpre[b];
#pragma unroll
    for (int i = 0; i < 4; ++i) {
        int idx = base + i;
        if (idx < n) { rowstart[idx] = excl; cursor[idx] = excl; }
        excl += v[i];
    }
    if (b == 0 && t == 0) rowstart[n] = e;
}

__global__ void fill_kernel(const int* __restrict__ rows, const int* __restrict__ cols,
                            int* __restrict__ cursor, int* __restrict__ csr, int e) {
    int i = blockIdx.x * blockDim.x + threadIdx.x;
    if (i >= e) return;
    int pos = atomicAdd(&cursor[cols[i]], 1);
    csr[pos] = rows[i];
}

// ---------------- fused MLP + riemann + init ----------------
// block = 256 threads handles 64 rows. GEMM1: thread (tr,th) owns 4 rows x 4 hid.
// x staged transposed (xt[k][row], pad 68); W1 tile in LDS. Epilogue: relu ->
// hs (reuse xt) -> GEMM2 (W2 in LDS) -> riemann -> hidden = temp0*hn, g0 = dis*hn.

__global__ __launch_bounds__(256) void mlp_kernel(
    const float* __restrict__ x, const float* __restrict__ W1,
    const float* __restrict__ b1, const float* __restrict__ W2,
    const float* __restrict__ b2, const float* __restrict__ dis,
    const float* __restrict__ temp, const float* __restrict__ w_for_norm,
    float* __restrict__ g0, float* __restrict__ hidden, int n) {
    __shared__ float xt[64][PAD];
    __shared__ float w1s[64][PAD];
    __shared__ float w2s[64][16];

    const int t = threadIdx.x;
    const int row0 = blockIdx.x * 64;

    // stage W2 (64x16) once
    {
        float4 v = *(const float4*)(W2 + t * 4);
        *(float4*)&w2s[t >> 2][(t & 3) * 4] = v;
    }

    const int tr = t >> 4, th = t & 15;
    float acc[4][4];
#pragma unroll
    for (int i = 0; i < 4; ++i)
#pragma unroll
        for (int j = 0; j < 4; ++j) acc[i][j] = 0.0f;

    for (int c = 0; c < F_IN / 64; ++c) {
        __syncthreads();
        {   // stage x transposed: thread loads x[row][4k..] -> xt[k][row]
            const int k4 = t & 15, rl = t >> 4;
#pragma unroll
            for (int it = 0; it < 4; ++it) {
                int row = rl + 16 * it;
                int gr = row0 + row; if (gr >= n) gr = n - 1;
                float4 v = *(const float4*)(x + (long)gr * F_IN + c * 64 + k4 * 4);
                xt[k4 * 4 + 0][row] = v.x;
                xt[k4 * 4 + 1][row] = v.y;
                xt[k4 * 4 + 2][row] = v.z;
                xt[k4 * 4 + 3][row] = v.w;
            }
            // stage W1 tile [64k][64h]
            const int h4 = t & 15, kl = t >> 4;
#pragma unroll
            for (int it = 0; it < 4; ++it) {
                int kk = kl + 16 * it;
                float4 v = *(const float4*)(W1 + (long)(c * 64 + kk) * HD + h4 * 4);
                *(float4*)&w1s[kk][h4 * 4] = v;
            }
        }
        __syncthreads();
#pragma unroll 8
        for (int kk = 0; kk < 64; ++kk) {
            float4 xv = *(const float4*)&xt[kk][tr * 4];
            float4 wv = *(const float4*)&w1s[kk][th * 4];
            acc[0][0] = fmaf(xv.x, wv.x, acc[0][0]);
            acc[0][1] = fmaf(xv.x, wv.y, acc[0][1]);
            acc[0][2] = fmaf(xv.x, wv.z, acc[0][2]);
            acc[0][3] = fmaf(xv.x, wv.w, acc[0][3]);
            acc[1][0] = fmaf(xv.y, wv.x, acc[1][0]);
            acc[1][1] = fmaf(xv.y, wv.y, acc[1][1]);
            acc[1][2] = fmaf(xv.y, wv.z, acc[1][2]);
            acc[1][3] = fmaf(xv.y, wv.w, acc[1][3]);
            acc[2][0] = fmaf(xv.z, wv.x, acc[2][0]);
            acc[2][1] = fmaf(xv.z, wv.y, acc[2][1]);
            acc[2][2] = fmaf(xv.z, wv.z, acc[2][2]);
            acc[2][3] = fmaf(xv.z, wv.w, acc[2][3]);
            acc[3][0] = fmaf(xv.w, wv.x, acc[3][0]);
            acc[3][1] = fmaf(xv.w, wv.y, acc[3][1]);
            acc[3][2] = fmaf(xv.w, wv.z, acc[3][2]);
            acc[3][3] = fmaf(xv.w, wv.w, acc[3][3]);
        }
    }

    // bias + relu -> hs (reuse xt as hs[row][hid])
    __syncthreads();
    {
        float4 bv = *(const float4*)(b1 + th * 4);
        float bb[4] = {bv.x, bv.y, bv.z, bv.w};
#pragma unroll
        for (int i = 0; i < 4; ++i) {
            float4 hv;
            hv.x = acc[i][0] + bb[0]; hv.x = hv.x > 0.f ? hv.x : 0.f;
            hv.y = acc[i][1] + bb[1]; hv.y = hv.y > 0.f ? hv.y : 0.f;
            hv.z = acc[i][2] + bb[2]; hv.z = hv.z > 0.f ? hv.z : 0.f;
            hv.w = acc[i][3] + bb[3]; hv.w = hv.w > 0.f ? hv.w : 0.f;
            *(float4*)&xt[tr * 4 + i][th * 4] = hv;
        }
    }
    __syncthreads();

    // GEMM2: thread = (row r, out-quad oq)
    {
        const int r = t >> 2, oq = t & 3;
        float4 b2v = *(const float4*)(b2 + oq * 4);
        float o[4] = {b2v.x, b2v.y, b2v.z, b2v.w};
#pragma unroll 8
        for (int k = 0; k < HD; ++k) {
            float hv = xt[r][k];
            float4 wv = *(const float4*)&w2s[k][oq * 4];
            o[0] = fmaf(hv, wv.x, o[0]);
            o[1] = fmaf(hv, wv.y, o[1]);
            o[2] = fmaf(hv, wv.z, o[2]);
            o[3] = fmaf(hv, wv.w, o[3]);
        }
        // riemann over 4-lane group
        float4 wn = *(const float4*)(w_for_norm + oq * 4);
        float p = o[0] * o[0] * fabsf(wn.x) + o[1] * o[1] * fabsf(wn.y) +
                  o[2] * o[2] * fabsf(wn.z) + o[3] * o[3] * fabsf(wn.w);
        p += __shfl_xor(p, 1);
        p += __shfl_xor(p, 2);
        float inv = 1.0f / (sqrtf(p + 0.01f) + 0.01f);
        int grow = row0 + r;
        if (grow < n) {
            float t0 = temp[0];
            float d = dis[grow];
            float hn0 = o[0] * inv, hn1 = o[1] * inv, hn2 = o[2] * inv, hn3 = o[3] * inv;
            *(float4*)(hidden + (long)grow * CD + oq * 4) =
                make_float4(t0 * hn0, t0 * hn1, t0 * hn2, t0 * hn3);
            *(float4*)(g0 + (long)grow * CD + oq * 4) =
                make_float4(d * hn0, d * hn1, d * hn2, d * hn3);
        }
    }
}

// ---------------- fused hop: CSR gather + riemann + hidden accum ----------
// 16 lanes per node (one feature each). g = dis*h_norm, so
// agg = dis[node] * (g[node] + sum_{src in N(node)} g[src]).

__global__ __launch_bounds__(256) void hop_kernel(
    const float* __restrict__ g, float* __restrict__ gn,
    float* __restrict__ hidden, const float* __restrict__ dis,
    const int* __restrict__ rowstart, const int* __restrict__ csr,
    const float* __restrict__ temp, const float* __restrict__ w_for_norm,
    int kidx, int writeg, int n) {
    int tt = blockIdx.x * blockDim.x + threadIdx.x;
    int node = tt >> 4, f = tt & 15;
    if (node >= n) return;
    long base = (long)node * CD + f;
    float acc = g[base];  // self-loop term
    int rs0 = rowstart[node], rs1 = rowstart[node + 1];
    for (int e = rs0; e < rs1; ++e) {
        int s = csr[e];
        acc += g[(long)s * CD + f];
    }
    float a = dis[node] * acc;
    float p = a * a * fabsf(w_for_norm[f]);
    p += __shfl_xor(p, 1);
    p += __shfl_xor(p, 2);
    p += __shfl_xor(p, 4);
    p += __shfl_xor(p, 8);
    float hn = a / (sqrtf(p + 0.01f) + 0.01f);
    hidden[base] += temp[kidx] * hn;
    if (writeg) gn[base] = dis[node] * hn;
}

// ---------------- launch ----------------

static inline long align4up(long w) { return (w + 3) & ~3L; }

extern "C" void kernel_launch(void* const* d_in, const int* in_sizes, int n_in,
                              void* d_out, int out_size, void* d_ws, size_t ws_size,
                              hipStream_t stream) {
    const float* x          = (const float*)d_in[0];
    const int*   edge_index = (const int*)d_in[1];
    const float* W1         = (const float*)d_in[2];
    const float* b1         = (const float*)d_in[3];
    const float* W2         = (const float*)d_in[4];
    const float* b2         = (const float*)d_in[5];
    const float* temp       = (const float*)d_in[6];
    const float* w_for_norm = (const float*)d_in[7];
    float* hidden = (float*)d_out;

    const int n = in_sizes[0] / F_IN;
    const int e = in_sizes[1] / 2;
    const int* rows = edge_index;        // sources
    const int* cols = edge_index + e;    // destinations

    // workspace layout (4-byte words, 16B-aligned sections)
    long off = 0;
    int* wsI = (int*)d_ws;
    int* degi     = wsI + off; off = align4up(off + n);
    int* rowstart = wsI + off; off = align4up(off + n + 1);
    int* cursor   = wsI + off; off = align4up(off + n);
    int* bsum     = wsI + off; off = align4up(off + 256);
    int* bpre     = wsI + off; off = align4up(off + 256);
    int* csr      = wsI + off; off = align4up(off + e);
    float* dis    = (float*)(wsI + off); off = align4up(off + n);
    float* gA     = (float*)(wsI + off); off = align4up(off + (long)n * CD);
    float* gB     = (float*)(wsI + off); off = align4up(off + (long)n * CD);

    const int B = 256;
    const int nb = (n + 1023) / 1024;

    zero_int_kernel<<<(n + B - 1) / B, B, 0, stream>>>(degi, n);
    hist_kernel<<<(e + B - 1) / B, B, 0, stream>>>(cols, degi, e);
    dis_kernel<<<(n + B - 1) / B, B, 0, stream>>>(degi, dis, n);
    scan1_kernel<<<nb, B, 0, stream>>>(degi, bsum, n);
    scan2_kernel<<<1, B, 0, stream>>>(bsum, bpre, nb);
    scan3_kernel<<<nb, B, 0, stream>>>(degi, bpre, rowstart, cursor, n, e);
    fill_kernel<<<(e + B - 1) / B, B, 0, stream>>>(rows, cols, cursor, csr, e);

    mlp_kernel<<<(n + 63) / 64, B, 0, stream>>>(x, W1, b1, W2, b2, dis, temp,
                                                w_for_norm, gA, hidden, n);

    float* gsrc = gA;
    float* gdst = gB;
    for (int k = 1; k <= K_HOPS; ++k) {
        hop_kernel<<<((long)16 * n + B - 1) / B, B, 0, stream>>>(
            gsrc, gdst, hidden, dis, rowstart, csr, temp, w_for_norm,
            k, (k < K_HOPS) ? 1 : 0, n);
        float* tmp = gsrc; gsrc = gdst; gdst = tmp;
    }
}

// Round 3
// 784.133 us; speedup vs baseline: 9.1994x; 1.8886x over previous
//
#include <hip/hip_runtime.h>
#include <math.h>

#define F_IN 512
#define HD 64
#define CD 16
#define K_HOPS 10
#define PAD 68

#define BKT_SHIFT 7
#define BKT_NODES 128
#define NBKT_MAX 1024
#define EPB 8192

typedef unsigned int uint32;
typedef unsigned short ushort16;

static __device__ __forceinline__ float bf2f(unsigned short h) {
    return __uint_as_float(((uint32)h) << 16);
}
static __device__ __forceinline__ unsigned short f2bf(float x) {
    uint32 u = __float_as_uint(x);
    u = (u + 0x7FFFu + ((u >> 16) & 1u)) >> 16;   // RNE
    return (unsigned short)u;
}

// ---------------- CSR build: two-level bucket sort ----------------

__global__ void zero_kernel(int* __restrict__ p, int n) {
    int i = blockIdx.x * blockDim.x + threadIdx.x;
    if (i < n) p[i] = 0;
}

// A: global bucket histogram (LDS-aggregated)
__global__ __launch_bounds__(256) void bucket_hist_kernel(
    const int* __restrict__ cols, int* __restrict__ bcnt, int e, int nb) {
    __shared__ int c[NBKT_MAX];
    int t = threadIdx.x;
    for (int i = t; i < nb; i += 256) c[i] = 0;
    __syncthreads();
    int base = blockIdx.x * EPB;
    int end = min(base + EPB, e);
    for (int i = base + t; i < end; i += 256)
        atomicAdd(&c[cols[i] >> BKT_SHIFT], 1);
    __syncthreads();
    for (int i = t; i < nb; i += 256)
        if (c[i]) atomicAdd(&bcnt[i], c[i]);
}

// B: scan bucket counts -> bstart[nb+1]; init bcur = bstart
__global__ __launch_bounds__(256) void bucket_scan_kernel(
    const int* __restrict__ bcnt, int* __restrict__ bstart,
    int* __restrict__ bcur, int nb) {
    __shared__ int s[256];
    int t = threadIdx.x;
    int v[4]; int sum = 0;
#pragma unroll
    for (int i = 0; i < 4; ++i) {
        int idx = t * 4 + i;
        v[i] = (idx < nb) ? bcnt[idx] : 0;
        sum += v[i];
    }
    s[t] = sum; __syncthreads();
    for (int off = 1; off < 256; off <<= 1) {
        int x = (t >= off) ? s[t - off] : 0;
        __syncthreads();
        s[t] += x;
        __syncthreads();
    }
    int excl = s[t] - sum;
#pragma unroll
    for (int i = 0; i < 4; ++i) {
        int idx = t * 4 + i;
        if (idx < nb) { bstart[idx] = excl; bcur[idx] = excl; }
        excl += v[i];
    }
    if (t == 255) bstart[nb] = excl;   // == e
}

// C: block-binned scatter into staging (payload = src<<7 | (col&127))
__global__ __launch_bounds__(256) void scatter_bin_kernel(
    const int* __restrict__ rows, const int* __restrict__ cols,
    int* __restrict__ bcur, uint32* __restrict__ stage, int e, int nb) {
    __shared__ int c[NBKT_MAX];
    int t = threadIdx.x;
    for (int i = t; i < nb; i += 256) c[i] = 0;
    __syncthreads();
    int base = blockIdx.x * EPB;
    int end = min(base + EPB, e);
    for (int i = base + t; i < end; i += 256)
        atomicAdd(&c[cols[i] >> BKT_SHIFT], 1);
    __syncthreads();
    for (int i = t; i < nb; i += 256) {
        int cc = c[i];
        if (cc) c[i] = atomicAdd(&bcur[i], cc);   // count -> block's base cursor
    }
    __syncthreads();
    for (int i = base + t; i < end; i += 256) {
        int col = cols[i];
        int b = col >> BKT_SHIFT;
        int pos = atomicAdd(&c[b], 1);
        stage[pos] = ((uint32)rows[i] << BKT_SHIFT) | (uint32)(col & (BKT_NODES - 1));
    }
}

// D: per-bucket counting sort -> csr, rowstart, dis
__global__ __launch_bounds__(256) void bucket_sort_kernel(
    const uint32* __restrict__ stage, const int* __restrict__ bstart,
    int* __restrict__ rowstart, float* __restrict__ dis,
    int* __restrict__ csr, int n, int e) {
    __shared__ int cnt[BKT_NODES];
    __shared__ int excl[BKT_NODES];
    __shared__ int lcur[BKT_NODES];
    int b = blockIdx.x, t = threadIdx.x;
    int s0 = bstart[b], s1 = bstart[b + 1];
    int nnode = min(BKT_NODES, n - b * BKT_NODES);
    if (t < BKT_NODES) cnt[t] = 0;
    __syncthreads();
    for (int i = s0 + t; i < s1; i += 256)
        atomicAdd(&cnt[stage[i] & (BKT_NODES - 1)], 1);
    __syncthreads();
    if (t < BKT_NODES) excl[t] = cnt[t];
    __syncthreads();
    for (int off = 1; off < BKT_NODES; off <<= 1) {
        int x = 0;
        if (t < BKT_NODES && t >= off) x = excl[t - off];
        __syncthreads();
        if (t < BKT_NODES) excl[t] += x;
        __syncthreads();
    }
    if (t < BKT_NODES) {
        int rs = s0 + excl[t] - cnt[t];     // exclusive
        lcur[t] = rs;
        if (t < nnode) {
            rowstart[b * BKT_NODES + t] = rs;
            dis[b * BKT_NODES + t] = rsqrtf((float)(cnt[t] + 1));
        }
    }
    if (b == 0 && t == 0) rowstart[n] = e;
    __syncthreads();
    for (int i = s0 + t; i < s1; i += 256) {
        uint32 v = stage[i];
        int pos = atomicAdd(&lcur[v & (BKT_NODES - 1)], 1);
        csr[pos] = (int)(v >> BKT_SHIFT);
    }
}

// ---------------- fused MLP + riemann + init ----------------

__global__ __launch_bounds__(256) void mlp_kernel(
    const float* __restrict__ x, const float* __restrict__ W1,
    const float* __restrict__ b1, const float* __restrict__ W2,
    const float* __restrict__ b2, const float* __restrict__ dis,
    const float* __restrict__ temp, const float* __restrict__ w_for_norm,
    unsigned short* __restrict__ g0, float* __restrict__ hidden, int n) {
    __shared__ float xt[64][PAD];
    __shared__ float w1s[64][PAD];
    __shared__ float w2s[64][16];

    const int t = threadIdx.x;
    const int row0 = blockIdx.x * 64;

    {
        float4 v = *(const float4*)(W2 + t * 4);
        *(float4*)&w2s[t >> 2][(t & 3) * 4] = v;
    }

    const int tr = t >> 4, th = t & 15;
    float acc[4][4];
#pragma unroll
    for (int i = 0; i < 4; ++i)
#pragma unroll
        for (int j = 0; j < 4; ++j) acc[i][j] = 0.0f;

    for (int c = 0; c < F_IN / 64; ++c) {
        __syncthreads();
        {
            const int k4 = t & 15, rl = t >> 4;
#pragma unroll
            for (int it = 0; it < 4; ++it) {
                int row = rl + 16 * it;
                int gr = row0 + row; if (gr >= n) gr = n - 1;
                float4 v = *(const float4*)(x + (long)gr * F_IN + c * 64 + k4 * 4);
                xt[k4 * 4 + 0][row] = v.x;
                xt[k4 * 4 + 1][row] = v.y;
                xt[k4 * 4 + 2][row] = v.z;
                xt[k4 * 4 + 3][row] = v.w;
            }
            const int h4 = t & 15, kl = t >> 4;
#pragma unroll
            for (int it = 0; it < 4; ++it) {
                int kk = kl + 16 * it;
                float4 v = *(const float4*)(W1 + (long)(c * 64 + kk) * HD + h4 * 4);
                *(float4*)&w1s[kk][h4 * 4] = v;
            }
        }
        __syncthreads();
#pragma unroll 8
        for (int kk = 0; kk < 64; ++kk) {
            float4 xv = *(const float4*)&xt[kk][tr * 4];
            float4 wv = *(const float4*)&w1s[kk][th * 4];
            acc[0][0] = fmaf(xv.x, wv.x, acc[0][0]);
            acc[0][1] = fmaf(xv.x, wv.y, acc[0][1]);
            acc[0][2] = fmaf(xv.x, wv.z, acc[0][2]);
            acc[0][3] = fmaf(xv.x, wv.w, acc[0][3]);
            acc[1][0] = fmaf(xv.y, wv.x, acc[1][0]);
            acc[1][1] = fmaf(xv.y, wv.y, acc[1][1]);
            acc[1][2] = fmaf(xv.y, wv.z, acc[1][2]);
            acc[1][3] = fmaf(xv.y, wv.w, acc[1][3]);
            acc[2][0] = fmaf(xv.z, wv.x, acc[2][0]);
            acc[2][1] = fmaf(xv.z, wv.y, acc[2][1]);
            acc[2][2] = fmaf(xv.z, wv.z, acc[2][2]);
            acc[2][3] = fmaf(xv.z, wv.w, acc[2][3]);
            acc[3][0] = fmaf(xv.w, wv.x, acc[3][0]);
            acc[3][1] = fmaf(xv.w, wv.y, acc[3][1]);
            acc[3][2] = fmaf(xv.w, wv.z, acc[3][2]);
            acc[3][3] = fmaf(xv.w, wv.w, acc[3][3]);
        }
    }

    __syncthreads();
    {
        float4 bv = *(const float4*)(b1 + th * 4);
        float bb[4] = {bv.x, bv.y, bv.z, bv.w};
#pragma unroll
        for (int i = 0; i < 4; ++i) {
            float4 hv;
            hv.x = acc[i][0] + bb[0]; hv.x = hv.x > 0.f ? hv.x : 0.f;
            hv.y = acc[i][1] + bb[1]; hv.y = hv.y > 0.f ? hv.y : 0.f;
            hv.z = acc[i][2] + bb[2]; hv.z = hv.z > 0.f ? hv.z : 0.f;
            hv.w = acc[i][3] + bb[3]; hv.w = hv.w > 0.f ? hv.w : 0.f;
            *(float4*)&xt[tr * 4 + i][th * 4] = hv;
        }
    }
    __syncthreads();

    {
        const int r = t >> 2, oq = t & 3;
        float4 b2v = *(const float4*)(b2 + oq * 4);
        float o[4] = {b2v.x, b2v.y, b2v.z, b2v.w};
#pragma unroll 8
        for (int k = 0; k < HD; ++k) {
            float hv = xt[r][k];
            float4 wv = *(const float4*)&w2s[k][oq * 4];
            o[0] = fmaf(hv, wv.x, o[0]);
            o[1] = fmaf(hv, wv.y, o[1]);
            o[2] = fmaf(hv, wv.z, o[2]);
            o[3] = fmaf(hv, wv.w, o[3]);
        }
        float4 wn = *(const float4*)(w_for_norm + oq * 4);
        float p = o[0] * o[0] * fabsf(wn.x) + o[1] * o[1] * fabsf(wn.y) +
                  o[2] * o[2] * fabsf(wn.z) + o[3] * o[3] * fabsf(wn.w);
        p += __shfl_xor(p, 1);
        p += __shfl_xor(p, 2);
        float inv = 1.0f / (sqrtf(p + 0.01f) + 0.01f);
        int grow = row0 + r;
        if (grow < n) {
            float t0 = temp[0];
            float d = dis[grow];
            float hn0 = o[0] * inv, hn1 = o[1] * inv, hn2 = o[2] * inv, hn3 = o[3] * inv;
            *(float4*)(hidden + (long)grow * CD + oq * 4) =
                make_float4(t0 * hn0, t0 * hn1, t0 * hn2, t0 * hn3);
            ushort4 ov;
            ov.x = f2bf(d * hn0); ov.y = f2bf(d * hn1);
            ov.z = f2bf(d * hn2); ov.w = f2bf(d * hn3);
            *(ushort4*)(g0 + (long)grow * CD + oq * 4) = ov;
        }
    }
}

// ---------------- fused hop: one wave per node, 8 edge-groups x 8 feat-lanes

__global__ __launch_bounds__(256) void hop_kernel(
    const unsigned short* __restrict__ g, unsigned short* __restrict__ gn,
    float* __restrict__ hidden, const float* __restrict__ dis,
    const int* __restrict__ rowstart, const int* __restrict__ csr,
    const float* __restrict__ temp, const float* __restrict__ wfn,
    int kidx, int writeg, int n) {
    int wid = (blockIdx.x << 2) + (threadIdx.x >> 6);
    if (wid >= n) return;
    int lane = threadIdx.x & 63;
    int grp = lane >> 3, fl = lane & 7;

    int rs0 = rowstart[wid], rs1 = rowstart[wid + 1];
    float a0 = 0.f, a1 = 0.f;
    for (int e = rs0 + grp; e < rs1; e += 8) {
        int s = csr[e];
        ushort2 v = *(const ushort2*)(g + ((long)s << 4) + (fl << 1));
        a0 += bf2f(v.x);
        a1 += bf2f(v.y);
    }
    a0 += __shfl_xor(a0, 8);  a1 += __shfl_xor(a1, 8);
    a0 += __shfl_xor(a0, 16); a1 += __shfl_xor(a1, 16);
    a0 += __shfl_xor(a0, 32); a1 += __shfl_xor(a1, 32);

    ushort2 sv = *(const ushort2*)(g + ((long)wid << 4) + (fl << 1));
    a0 += bf2f(sv.x);
    a1 += bf2f(sv.y);

    float d = dis[wid];
    a0 *= d; a1 *= d;

    float2 w = *(const float2*)(wfn + (fl << 1));
    float p = a0 * a0 * fabsf(w.x) + a1 * a1 * fabsf(w.y);
    p += __shfl_xor(p, 1);
    p += __shfl_xor(p, 2);
    p += __shfl_xor(p, 4);
    float inv = 1.0f / (sqrtf(p + 0.01f) + 0.01f);
    float h0 = a0 * inv, h1 = a1 * inv;

    if (grp == 0) {
        float tk = temp[kidx];
        float2* hp = (float2*)(hidden + ((long)wid << 4) + (fl << 1));
        float2 hv = *hp;
        hv.x = fmaf(tk, h0, hv.x);
        hv.y = fmaf(tk, h1, hv.y);
        *hp = hv;
        if (writeg) {
            ushort2 o;
            o.x = f2bf(d * h0);
            o.y = f2bf(d * h1);
            *(ushort2*)(gn + ((long)wid << 4) + (fl << 1)) = o;
        }
    }
}

// ---------------- launch ----------------

static inline long align4up(long w) { return (w + 3) & ~3L; }

extern "C" void kernel_launch(void* const* d_in, const int* in_sizes, int n_in,
                              void* d_out, int out_size, void* d_ws, size_t ws_size,
                              hipStream_t stream) {
    const float* x          = (const float*)d_in[0];
    const int*   edge_index = (const int*)d_in[1];
    const float* W1         = (const float*)d_in[2];
    const float* b1         = (const float*)d_in[3];
    const float* W2         = (const float*)d_in[4];
    const float* b2         = (const float*)d_in[5];
    const float* temp       = (const float*)d_in[6];
    const float* w_for_norm = (const float*)d_in[7];
    float* hidden = (float*)d_out;

    const int n = in_sizes[0] / F_IN;
    const int e = in_sizes[1] / 2;
    const int* rows = edge_index;        // sources
    const int* cols = edge_index + e;    // destinations
    const int nb = (n + BKT_NODES - 1) / BKT_NODES;

    long off = 0;
    int* wsI = (int*)d_ws;
    int* bcnt      = wsI + off; off = align4up(off + NBKT_MAX);
    int* bstart    = wsI + off; off = align4up(off + NBKT_MAX + 1);
    int* bcur      = wsI + off; off = align4up(off + NBKT_MAX);
    int* rowstart  = wsI + off; off = align4up(off + n + 1);
    float* dis     = (float*)(wsI + off); off = align4up(off + n);
    uint32* stage  = (uint32*)(wsI + off); off = align4up(off + e);
    int* csr       = wsI + off; off = align4up(off + e);
    unsigned short* gA = (unsigned short*)(wsI + off); off = align4up(off + n * 8);
    unsigned short* gB = (unsigned short*)(wsI + off); off = align4up(off + n * 8);

    const int B = 256;
    const int nbC = (e + EPB - 1) / EPB;

    zero_kernel<<<(nb + B - 1) / B, B, 0, stream>>>(bcnt, nb);
    bucket_hist_kernel<<<nbC, B, 0, stream>>>(cols, bcnt, e, nb);
    bucket_scan_kernel<<<1, B, 0, stream>>>(bcnt, bstart, bcur, nb);
    scatter_bin_kernel<<<nbC, B, 0, stream>>>(rows, cols, bcur, stage, e, nb);
    bucket_sort_kernel<<<nb, B, 0, stream>>>(stage, bstart, rowstart, dis, csr, n, e);

    mlp_kernel<<<(n + 63) / 64, B, 0, stream>>>(x, W1, b1, W2, b2, dis, temp,
                                                w_for_norm, gA, hidden, n);

    unsigned short* gsrc = gA;
    unsigned short* gdst = gB;
    for (int k = 1; k <= K_HOPS; ++k) {
        hop_kernel<<<(n + 3) / 4, B, 0, stream>>>(
            gsrc, gdst, hidden, dis, rowstart, csr, temp, w_for_norm,
            k, (k < K_HOPS) ? 1 : 0, n);
        unsigned short* tmp = gsrc; gsrc = gdst; gdst = tmp;
    }
}

// Round 4
// 658.623 us; speedup vs baseline: 10.9525x; 1.1906x over previous
//
#include <hip/hip_runtime.h>
#include <math.h>

#define F_IN 512
#define HD 64
#define CD 16
#define K_HOPS 10
#define PAD 68

#define BKT_SHIFT 7
#define BKT_NODES 128
#define NBKT_MAX 1024
#define EPB 8192

typedef unsigned int uint32;

static __device__ __forceinline__ float bf2f(unsigned short h) {
    return __uint_as_float(((uint32)h) << 16);
}
static __device__ __forceinline__ unsigned short f2bf(float x) {
    uint32 u = __float_as_uint(x);
    u = (u + 0x7FFFu + ((u >> 16) & 1u)) >> 16;   // RNE
    return (unsigned short)u;
}

// ---------------- CSR build: two-level bucket sort ----------------

__global__ void zero_kernel(int* __restrict__ p, int n) {
    int i = blockIdx.x * blockDim.x + threadIdx.x;
    if (i < n) p[i] = 0;
}

__global__ __launch_bounds__(256) void bucket_hist_kernel(
    const int* __restrict__ cols, int* __restrict__ bcnt, int e, int nb) {
    __shared__ int c[NBKT_MAX];
    int t = threadIdx.x;
    for (int i = t; i < nb; i += 256) c[i] = 0;
    __syncthreads();
    int base = blockIdx.x * EPB;
    int end = min(base + EPB, e);
    for (int i = base + t; i < end; i += 256)
        atomicAdd(&c[cols[i] >> BKT_SHIFT], 1);
    __syncthreads();
    for (int i = t; i < nb; i += 256)
        if (c[i]) atomicAdd(&bcnt[i], c[i]);
}

__global__ __launch_bounds__(256) void bucket_scan_kernel(
    const int* __restrict__ bcnt, int* __restrict__ bstart,
    int* __restrict__ bcur, int nb) {
    __shared__ int s[256];
    int t = threadIdx.x;
    int v[4]; int sum = 0;
#pragma unroll
    for (int i = 0; i < 4; ++i) {
        int idx = t * 4 + i;
        v[i] = (idx < nb) ? bcnt[idx] : 0;
        sum += v[i];
    }
    s[t] = sum; __syncthreads();
    for (int off = 1; off < 256; off <<= 1) {
        int x = (t >= off) ? s[t - off] : 0;
        __syncthreads();
        s[t] += x;
        __syncthreads();
    }
    int excl = s[t] - sum;
#pragma unroll
    for (int i = 0; i < 4; ++i) {
        int idx = t * 4 + i;
        if (idx < nb) { bstart[idx] = excl; bcur[idx] = excl; }
        excl += v[i];
    }
    if (t == 255) bstart[nb] = excl;
}

__global__ __launch_bounds__(256) void scatter_bin_kernel(
    const int* __restrict__ rows, const int* __restrict__ cols,
    int* __restrict__ bcur, uint32* __restrict__ stage, int e, int nb) {
    __shared__ int c[NBKT_MAX];
    int t = threadIdx.x;
    for (int i = t; i < nb; i += 256) c[i] = 0;
    __syncthreads();
    int base = blockIdx.x * EPB;
    int end = min(base + EPB, e);
    for (int i = base + t; i < end; i += 256)
        atomicAdd(&c[cols[i] >> BKT_SHIFT], 1);
    __syncthreads();
    for (int i = t; i < nb; i += 256) {
        int cc = c[i];
        if (cc) c[i] = atomicAdd(&bcur[i], cc);
    }
    __syncthreads();
    for (int i = base + t; i < end; i += 256) {
        int col = cols[i];
        int b = col >> BKT_SHIFT;
        int pos = atomicAdd(&c[b], 1);
        stage[pos] = ((uint32)rows[i] << BKT_SHIFT) | (uint32)(col & (BKT_NODES - 1));
    }
}

__global__ __launch_bounds__(256) void bucket_sort_kernel(
    const uint32* __restrict__ stage, const int* __restrict__ bstart,
    int* __restrict__ rowstart, float* __restrict__ dis,
    int* __restrict__ csr, int n, int e) {
    __shared__ int cnt[BKT_NODES];
    __shared__ int excl[BKT_NODES];
    __shared__ int lcur[BKT_NODES];
    int b = blockIdx.x, t = threadIdx.x;
    int s0 = bstart[b], s1 = bstart[b + 1];
    int nnode = min(BKT_NODES, n - b * BKT_NODES);
    if (t < BKT_NODES) cnt[t] = 0;
    __syncthreads();
    for (int i = s0 + t; i < s1; i += 256)
        atomicAdd(&cnt[stage[i] & (BKT_NODES - 1)], 1);
    __syncthreads();
    if (t < BKT_NODES) excl[t] = cnt[t];
    __syncthreads();
    for (int off = 1; off < BKT_NODES; off <<= 1) {
        int x = 0;
        if (t < BKT_NODES && t >= off) x = excl[t - off];
        __syncthreads();
        if (t < BKT_NODES) excl[t] += x;
        __syncthreads();
    }
    if (t < BKT_NODES) {
        int rs = s0 + excl[t] - cnt[t];
        lcur[t] = rs;
        if (t < nnode) {
            rowstart[b * BKT_NODES + t] = rs;
            dis[b * BKT_NODES + t] = rsqrtf((float)(cnt[t] + 1));
        }
    }
    if (b == 0 && t == 0) rowstart[n] = e;
    __syncthreads();
    for (int i = s0 + t; i < s1; i += 256) {
        uint32 v = stage[i];
        int pos = atomicAdd(&lcur[v & (BKT_NODES - 1)], 1);
        csr[pos] = (int)(v >> BKT_SHIFT);
    }
}

// ---------------- fused MLP + riemann + init ----------------
// xt staging uses XOR swizzle col ^ (4*((k>>2)&7)) to kill the 8-way
// bank conflict of the stride-68 transpose store (write now covers all
// 32 banks 2-way; GEMM read stays a 16-lane broadcast, 16B-aligned).

__global__ __launch_bounds__(256) void mlp_kernel(
    const float* __restrict__ x, const float* __restrict__ W1,
    const float* __restrict__ b1, const float* __restrict__ W2,
    const float* __restrict__ b2, const float* __restrict__ dis,
    const float* __restrict__ temp, const float* __restrict__ w_for_norm,
    unsigned short* __restrict__ g0, float* __restrict__ hidden, int n) {
    __shared__ float xt[64][PAD];
    __shared__ float w1s[64][PAD];
    __shared__ float w2s[64][16];

    const int t = threadIdx.x;
    const int row0 = blockIdx.x * 64;

    {
        float4 v = *(const float4*)(W2 + t * 4);
        *(float4*)&w2s[t >> 2][(t & 3) * 4] = v;
    }

    const int tr = t >> 4, th = t & 15;
    float acc[4][4];
#pragma unroll
    for (int i = 0; i < 4; ++i)
#pragma unroll
        for (int j = 0; j < 4; ++j) acc[i][j] = 0.0f;

    for (int c = 0; c < F_IN / 64; ++c) {
        __syncthreads();
        {
            const int k4 = t & 15, rl = t >> 4;
            const int swz = 4 * (k4 & 7);
#pragma unroll
            for (int it = 0; it < 4; ++it) {
                int row = rl + 16 * it;
                int gr = row0 + row; if (gr >= n) gr = n - 1;
                float4 v = *(const float4*)(x + (long)gr * F_IN + c * 64 + k4 * 4);
                xt[k4 * 4 + 0][row ^ swz] = v.x;
                xt[k4 * 4 + 1][row ^ swz] = v.y;
                xt[k4 * 4 + 2][row ^ swz] = v.z;
                xt[k4 * 4 + 3][row ^ swz] = v.w;
            }
            const int h4 = t & 15, kl = t >> 4;
#pragma unroll
            for (int it = 0; it < 4; ++it) {
                int kk = kl + 16 * it;
                float4 v = *(const float4*)(W1 + (long)(c * 64 + kk) * HD + h4 * 4);
                *(float4*)&w1s[kk][h4 * 4] = v;
            }
        }
        __syncthreads();
#pragma unroll 8
        for (int kk = 0; kk < 64; ++kk) {
            float4 xv = *(const float4*)&xt[kk][(tr * 4) ^ (4 * ((kk >> 2) & 7))];
            float4 wv = *(const float4*)&w1s[kk][th * 4];
            acc[0][0] = fmaf(xv.x, wv.x, acc[0][0]);
            acc[0][1] = fmaf(xv.x, wv.y, acc[0][1]);
            acc[0][2] = fmaf(xv.x, wv.z, acc[0][2]);
            acc[0][3] = fmaf(xv.x, wv.w, acc[0][3]);
            acc[1][0] = fmaf(xv.y, wv.x, acc[1][0]);
            acc[1][1] = fmaf(xv.y, wv.y, acc[1][1]);
            acc[1][2] = fmaf(xv.y, wv.z, acc[1][2]);
            acc[1][3] = fmaf(xv.y, wv.w, acc[1][3]);
            acc[2][0] = fmaf(xv.z, wv.x, acc[2][0]);
            acc[2][1] = fmaf(xv.z, wv.y, acc[2][1]);
            acc[2][2] = fmaf(xv.z, wv.z, acc[2][2]);
            acc[2][3] = fmaf(xv.z, wv.w, acc[2][3]);
            acc[3][0] = fmaf(xv.w, wv.x, acc[3][0]);
            acc[3][1] = fmaf(xv.w, wv.y, acc[3][1]);
            acc[3][2] = fmaf(xv.w, wv.z, acc[3][2]);
            acc[3][3] = fmaf(xv.w, wv.w, acc[3][3]);
        }
    }

    __syncthreads();
    {
        float4 bv = *(const float4*)(b1 + th * 4);
        float bb[4] = {bv.x, bv.y, bv.z, bv.w};
#pragma unroll
        for (int i = 0; i < 4; ++i) {
            float4 hv;
            hv.x = acc[i][0] + bb[0]; hv.x = hv.x > 0.f ? hv.x : 0.f;
            hv.y = acc[i][1] + bb[1]; hv.y = hv.y > 0.f ? hv.y : 0.f;
            hv.z = acc[i][2] + bb[2]; hv.z = hv.z > 0.f ? hv.z : 0.f;
            hv.w = acc[i][3] + bb[3]; hv.w = hv.w > 0.f ? hv.w : 0.f;
            *(float4*)&xt[tr * 4 + i][th * 4] = hv;
        }
    }
    __syncthreads();

    {
        const int r = t >> 2, oq = t & 3;
        float4 b2v = *(const float4*)(b2 + oq * 4);
        float o[4] = {b2v.x, b2v.y, b2v.z, b2v.w};
#pragma unroll 8
        for (int k = 0; k < HD; ++k) {
            float hv = xt[r][k];
            float4 wv = *(const float4*)&w2s[k][oq * 4];
            o[0] = fmaf(hv, wv.x, o[0]);
            o[1] = fmaf(hv, wv.y, o[1]);
            o[2] = fmaf(hv, wv.z, o[2]);
            o[3] = fmaf(hv, wv.w, o[3]);
        }
        float4 wn = *(const float4*)(w_for_norm + oq * 4);
        float p = o[0] * o[0] * fabsf(wn.x) + o[1] * o[1] * fabsf(wn.y) +
                  o[2] * o[2] * fabsf(wn.z) + o[3] * o[3] * fabsf(wn.w);
        p += __shfl_xor(p, 1);
        p += __shfl_xor(p, 2);
        float inv = 1.0f / (sqrtf(p + 0.01f) + 0.01f);
        int grow = row0 + r;
        if (grow < n) {
            float t0 = temp[0];
            float d = dis[grow];
            float hn0 = o[0] * inv, hn1 = o[1] * inv, hn2 = o[2] * inv, hn3 = o[3] * inv;
            *(float4*)(hidden + (long)grow * CD + oq * 4) =
                make_float4(t0 * hn0, t0 * hn1, t0 * hn2, t0 * hn3);
            ushort4 ov;
            ov.x = f2bf(d * hn0); ov.y = f2bf(d * hn1);
            ov.z = f2bf(d * hn2); ov.w = f2bf(d * hn3);
            *(ushort4*)(g0 + (long)grow * CD + oq * 4) = ov;
        }
    }
}

// ---------------- fused hop: wave/node, 16 edge-slots x 4 feat-lanes -----
// 2-deep unrolled gather loop: 32 edges (csr + g) in flight before any
// accumulation -> ~1 dependent L2 round per average-degree node.

__global__ __launch_bounds__(256) void hop_kernel(
    const unsigned short* __restrict__ g, unsigned short* __restrict__ gn,
    float* __restrict__ hidden, const float* __restrict__ dis,
    const int* __restrict__ rowstart, const int* __restrict__ csr,
    const float* __restrict__ temp, const float* __restrict__ wfn,
    int kidx, int writeg, int n) {
    int wid = (blockIdx.x << 2) + (threadIdx.x >> 6);
    if (wid >= n) return;
    int lane = threadIdx.x & 63;
    int slot = lane >> 2, fl = lane & 3;   // 16 slots x 4 feat-lanes

    int rs0 = rowstart[wid], rs1 = rowstart[wid + 1];
    // independent loads issued early
    ushort4 sv = *(const ushort4*)(g + ((long)wid << 4) + (fl << 2));
    float d = dis[wid];
    float4 w = *(const float4*)(wfn + (fl << 2));

    float a0 = 0.f, a1 = 0.f, a2 = 0.f, a3 = 0.f;
    int e = rs0 + slot;
    while (e + 16 < rs1) {
        int s1 = csr[e];
        int s2 = csr[e + 16];
        ushort4 v1 = *(const ushort4*)(g + ((long)s1 << 4) + (fl << 2));
        ushort4 v2 = *(const ushort4*)(g + ((long)s2 << 4) + (fl << 2));
        a0 += bf2f(v1.x); a1 += bf2f(v1.y); a2 += bf2f(v1.z); a3 += bf2f(v1.w);
        a0 += bf2f(v2.x); a1 += bf2f(v2.y); a2 += bf2f(v2.z); a3 += bf2f(v2.w);
        e += 32;
    }
    if (e < rs1) {
        int s1 = csr[e];
        ushort4 v1 = *(const ushort4*)(g + ((long)s1 << 4) + (fl << 2));
        a0 += bf2f(v1.x); a1 += bf2f(v1.y); a2 += bf2f(v1.z); a3 += bf2f(v1.w);
    }

    // reduce over 16 slots (butterfly -> all lanes hold totals)
#pragma unroll
    for (int off = 4; off < 64; off <<= 1) {
        a0 += __shfl_xor(a0, off);
        a1 += __shfl_xor(a1, off);
        a2 += __shfl_xor(a2, off);
        a3 += __shfl_xor(a3, off);
    }

    // self-loop term + dis scale
    a0 = (a0 + bf2f(sv.x)) * d;
    a1 = (a1 + bf2f(sv.y)) * d;
    a2 = (a2 + bf2f(sv.z)) * d;
    a3 = (a3 + bf2f(sv.w)) * d;

    float p = a0 * a0 * fabsf(w.x) + a1 * a1 * fabsf(w.y) +
              a2 * a2 * fabsf(w.z) + a3 * a3 * fabsf(w.w);
    p += __shfl_xor(p, 1);
    p += __shfl_xor(p, 2);
    float inv = 1.0f / (sqrtf(p + 0.01f) + 0.01f);
    float h0 = a0 * inv, h1 = a1 * inv, h2 = a2 * inv, h3 = a3 * inv;

    if (slot == 0) {
        float tk = temp[kidx];
        long base = ((long)wid << 4) + (fl << 2);
        float4* hp = (float4*)(hidden + base);
        float4 hv = *hp;
        hv.x = fmaf(tk, h0, hv.x);
        hv.y = fmaf(tk, h1, hv.y);
        hv.z = fmaf(tk, h2, hv.z);
        hv.w = fmaf(tk, h3, hv.w);
        *hp = hv;
        if (writeg) {
            ushort4 o;
            o.x = f2bf(d * h0); o.y = f2bf(d * h1);
            o.z = f2bf(d * h2); o.w = f2bf(d * h3);
            *(ushort4*)(gn + base) = o;
        }
    }
}

// ---------------- launch ----------------

static inline long align4up(long w) { return (w + 3) & ~3L; }

extern "C" void kernel_launch(void* const* d_in, const int* in_sizes, int n_in,
                              void* d_out, int out_size, void* d_ws, size_t ws_size,
                              hipStream_t stream) {
    const float* x          = (const float*)d_in[0];
    const int*   edge_index = (const int*)d_in[1];
    const float* W1         = (const float*)d_in[2];
    const float* b1         = (const float*)d_in[3];
    const float* W2         = (const float*)d_in[4];
    const float* b2         = (const float*)d_in[5];
    const float* temp       = (const float*)d_in[6];
    const float* w_for_norm = (const float*)d_in[7];
    float* hidden = (float*)d_out;

    const int n = in_sizes[0] / F_IN;
    const int e = in_sizes[1] / 2;
    const int* rows = edge_index;        // sources
    const int* cols = edge_index + e;    // destinations
    const int nb = (n + BKT_NODES - 1) / BKT_NODES;

    long off = 0;
    int* wsI = (int*)d_ws;
    int* bcnt      = wsI + off; off = align4up(off + NBKT_MAX);
    int* bstart    = wsI + off; off = align4up(off + NBKT_MAX + 1);
    int* bcur      = wsI + off; off = align4up(off + NBKT_MAX);
    int* rowstart  = wsI + off; off = align4up(off + n + 1);
    float* dis     = (float*)(wsI + off); off = align4up(off + n);
    uint32* stage  = (uint32*)(wsI + off); off = align4up(off + e);
    int* csr       = wsI + off; off = align4up(off + e);
    unsigned short* gA = (unsigned short*)(wsI + off); off = align4up(off + n * 8);
    unsigned short* gB = (unsigned short*)(wsI + off); off = align4up(off + n * 8);

    const int B = 256;
    const int nbC = (e + EPB - 1) / EPB;

    zero_kernel<<<(nb + B - 1) / B, B, 0, stream>>>(bcnt, nb);
    bucket_hist_kernel<<<nbC, B, 0, stream>>>(cols, bcnt, e, nb);
    bucket_scan_kernel<<<1, B, 0, stream>>>(bcnt, bstart, bcur, nb);
    scatter_bin_kernel<<<nbC, B, 0, stream>>>(rows, cols, bcur, stage, e, nb);
    bucket_sort_kernel<<<nb, B, 0, stream>>>(stage, bstart, rowstart, dis, csr, n, e);

    mlp_kernel<<<(n + 63) / 64, B, 0, stream>>>(x, W1, b1, W2, b2, dis, temp,
                                                w_for_norm, gA, hidden, n);

    unsigned short* gsrc = gA;
    unsigned short* gdst = gB;
    for (int k = 1; k <= K_HOPS; ++k) {
        hop_kernel<<<(n + 3) / 4, B, 0, stream>>>(
            gsrc, gdst, hidden, dis, rowstart, csr, temp, w_for_norm,
            k, (k < K_HOPS) ? 1 : 0, n);
        unsigned short* tmp = gsrc; gsrc = gdst; gdst = tmp;
    }
}